// Round 3
// baseline (12305.093 us; speedup 1.0000x reference)
//
#include <hip/hip_runtime.h>
#include <hip/hip_bf16.h>

// LightGCN 3-hop propagation, 150k nodes, 4.8M edges, EMB=64.
// Round 3: dtype-adaptive COO atomic-scatter SpMM, fp32 intermediates.
//   - on-device detection: float arrays bf16 vs fp32; edge_index int32 vs int64
//   - host-side ws_size guard writes sentinel ~1000.0 if workspace too small

#define NUM_USERS 100000
#define NUM_ITEMS 50000
#define N_NODES   150000
#define EMB       64
#define N_EDGES   4800000
#define NODE_ELEMS (N_NODES * EMB)   // 9,600,000
#define U_ELEMS    (NUM_USERS * EMB) // 6,400,000
#define I_ELEMS    (NUM_ITEMS * EMB) // 3,200,000

typedef __hip_bfloat16 bf16;

// flag bit0: float arrays are genuinely bf16 (else fp32 underneath)
// flag bit1: edge_index is int64 (else int32)
__global__ void detect_kernel(const unsigned short* __restrict__ u16,
                              const int* __restrict__ ei32,
                              int* __restrict__ flag)
{
    __shared__ int s_fp32, s_i32;
    if (threadIdx.x == 0) { s_fp32 = 0; s_i32 = 0; }
    __syncthreads();
    int t = threadIdx.x;                       // 256 threads, 1 block
    unsigned short u = u16[t];
    int e = (u >> 7) & 0xFF;                   // bf16 exponent field
    if (e >= 0xC0) atomicOr(&s_fp32, 1);       // |v| >= 2^65: impossible for real bf16 embeddings
    if (t < 64 && ei32[2 * t + 1] != 0) atomicOr(&s_i32, 1); // odd words nonzero => int32
    __syncthreads();
    if (t == 0) {
        int f = 0;
        if (!s_fp32) f |= 1;
        if (!s_i32)  f |= 2;
        *flag = f;
    }
}

// out layout (flat, element offsets identical for bf16/fp32):
//   [u_final | users_emb | i_final | items_emb]
__global__ void init_kernel(const void* __restrict__ users,
                            const void* __restrict__ items,
                            void* __restrict__ out,
                            float* __restrict__ A,
                            float* __restrict__ B,
                            float* __restrict__ ACC,
                            const int* __restrict__ flag)
{
    int gid = blockIdx.x * blockDim.x + threadIdx.x;
    if (gid >= NODE_ELEMS) return;
    const bool isb = ((*flag) & 1);
    float v;
    if (gid < U_ELEMS) {
        if (isb) {
            bf16 b = ((const bf16*)users)[gid];
            v = __bfloat162float(b);
            ((bf16*)out)[U_ELEMS + gid] = b;
        } else {
            float f = ((const float*)users)[gid];
            v = f;
            ((float*)out)[U_ELEMS + gid] = f;
        }
    } else {
        int ii = gid - U_ELEMS;
        if (isb) {
            bf16 b = ((const bf16*)items)[ii];
            v = __bfloat162float(b);
            ((bf16*)out)[2 * U_ELEMS + I_ELEMS + ii] = b;
        } else {
            float f = ((const float*)items)[ii];
            v = f;
            ((float*)out)[2 * U_ELEMS + I_ELEMS + ii] = f;
        }
    }
    A[gid]   = v;     // curr (hop input)
    B[gid]   = 0.0f;  // scatter target for hop 1
    ACC[gid] = v;     // acc = emb0
}

// 16 lanes per edge; lane j handles dims [4j, 4j+4). Consecutive 16 lanes
// read a contiguous 256B row of prev[col]; 4 fp32 HW atomics into next[row].
__global__ void scatter_kernel(const int* __restrict__ ei32,
                               const void* __restrict__ ew,
                               const float* __restrict__ prev,
                               float* __restrict__ next,
                               const int* __restrict__ flag)
{
    int gid = blockIdx.x * blockDim.x + threadIdx.x;
    if (gid >= N_EDGES * 16) return;            // 76.8M threads
    const int f = *flag;
    int e = gid >> 4;
    int j = (gid & 15) << 2;
    int row, col;
    if (f & 2) {  // int64: take low words (values < 2^31, nonnegative)
        row = ei32[2 * (size_t)e];
        col = ei32[2 * ((size_t)N_EDGES + e)];
    } else {      // int32
        row = ei32[e];
        col = ei32[N_EDGES + e];
    }
    float w = (f & 1) ? __bfloat162float(((const bf16*)ew)[e])
                      : ((const float*)ew)[e];
    const float4 v = *reinterpret_cast<const float4*>(prev + (size_t)col * EMB + j);
    float* dst = next + (size_t)row * EMB + j;
    unsafeAtomicAdd(dst + 0, w * v.x);
    unsafeAtomicAdd(dst + 1, w * v.y);
    unsafeAtomicAdd(dst + 2, w * v.z);
    unsafeAtomicAdd(dst + 3, w * v.w);
}

__global__ void accum_zero_kernel(float* __restrict__ acc,
                                  const float* __restrict__ next,
                                  float* __restrict__ prevz)
{
    int gid = blockIdx.x * blockDim.x + threadIdx.x;
    if (gid >= NODE_ELEMS) return;
    acc[gid] += next[gid];
    prevz[gid] = 0.0f;    // re-zero: becomes the scatter target next hop
}

__global__ void finalize_kernel(const float* __restrict__ acc,
                                void* __restrict__ out,
                                const int* __restrict__ flag)
{
    int gid = blockIdx.x * blockDim.x + threadIdx.x;
    if (gid >= NODE_ELEMS) return;
    const bool isb = ((*flag) & 1);
    float v = acc[gid] * 0.25f;
    size_t o = (gid < U_ELEMS) ? (size_t)gid
                               : (size_t)(2 * U_ELEMS + (gid - U_ELEMS));
    if (isb) ((bf16*)out)[o]  = __float2bfloat16(v);
    else     ((float*)out)[o] = v;
}

// diagnostic: ws too small -> absmax ~1000 regardless of out dtype
__global__ void sentinel_kernel(unsigned int* __restrict__ out, int nwords)
{
    int gid = blockIdx.x * blockDim.x + threadIdx.x;
    if (gid < nwords) out[gid] = 0x447A447Au;   // bf16 pair (1000,1000); fp32 ~1000.57
}

extern "C" void kernel_launch(void* const* d_in, const int* in_sizes, int n_in,
                              void* d_out, int out_size, void* d_ws, size_t ws_size,
                              hipStream_t stream)
{
    const void* users = d_in[0];
    const void* items = d_in[1];
    const int*  ei32  = (const int*)d_in[2];
    const void* ew    = d_in[3];

    char* wsb  = (char*)d_ws;
    int*  flag = (int*)wsb;
    float* A   = (float*)(wsb + 256);
    float* B   = A + (size_t)NODE_ELEMS;
    float* ACC = B + (size_t)NODE_ELEMS;

    const size_t need = 256 + 3 * (size_t)NODE_ELEMS * sizeof(float); // ~115.2 MB
    const int BLK = 256;

    if (ws_size < need) {
        int nwords = out_size / 2;   // write out_size*2 bytes: safe for bf16 or fp32 buffer
        sentinel_kernel<<<(nwords + BLK - 1) / BLK, BLK, 0, stream>>>((unsigned int*)d_out, nwords);
        return;
    }

    const int node_blocks = (NODE_ELEMS + BLK - 1) / BLK;       // 37,500
    const int edge_blocks = (N_EDGES * 16 + BLK - 1) / BLK;     // 300,000

    detect_kernel<<<1, BLK, 0, stream>>>((const unsigned short*)users, ei32, flag);
    init_kernel<<<node_blocks, BLK, 0, stream>>>(users, items, d_out, A, B, ACC, flag);

    float* prev = A;
    float* nxt  = B;
    for (int h = 0; h < 3; ++h) {
        scatter_kernel<<<edge_blocks, BLK, 0, stream>>>(ei32, ew, prev, nxt, flag);
        accum_zero_kernel<<<node_blocks, BLK, 0, stream>>>(ACC, nxt, prev);
        float* t = prev; prev = nxt; nxt = t;
    }

    finalize_kernel<<<node_blocks, BLK, 0, stream>>>(ACC, d_out, flag);
}

// Round 4
// 1541.906 us; speedup vs baseline: 7.9804x; 7.9804x over previous
//
#include <hip/hip_runtime.h>
#include <hip/hip_bf16.h>

// LightGCN 3-hop propagation, 150k nodes, 4.8M edges, EMB=64.
// Round 4: on-GPU CSR build + gather-only SpMM (no fp32 atomics in hops).
// R3 post-mortem: each fp32 atomic caused a 16B HBM write-through (4.8 GB/hop,
// 4 ms/hop). CSR hop writes 38.4 MB non-atomically instead.
// Keeps dtype-adaptive flag (bf16/fp32 floats, int32/int64 index) from R3.
// Falls back to R3 atomic path if ws_size < CSR layout size.

#define NUM_USERS 100000
#define NUM_ITEMS 50000
#define N_NODES   150000
#define EMB       64
#define N_EDGES   4800000
#define NODE_ELEMS (N_NODES * EMB)   // 9,600,000
#define U_ELEMS    (NUM_USERS * EMB) // 6,400,000
#define I_ELEMS    (NUM_ITEMS * EMB) // 3,200,000

typedef __hip_bfloat16 bf16;

// flag bit0: float arrays are bf16 (else fp32). bit1: edge_index int64 (else int32).
__global__ void detect_kernel(const unsigned short* __restrict__ u16,
                              const int* __restrict__ ei32,
                              int* __restrict__ flag)
{
    __shared__ int s_fp32, s_i32;
    if (threadIdx.x == 0) { s_fp32 = 0; s_i32 = 0; }
    __syncthreads();
    int t = threadIdx.x;
    unsigned short u = u16[t];
    int e = (u >> 7) & 0xFF;
    if (e >= 0xC0) atomicOr(&s_fp32, 1);
    if (t < 64 && ei32[2 * t + 1] != 0) atomicOr(&s_i32, 1);
    __syncthreads();
    if (t == 0) {
        int f = 0;
        if (!s_fp32) f |= 1;
        if (!s_i32)  f |= 2;
        *flag = f;
    }
}

__device__ __forceinline__ int load_row(const int* ei32, int f, size_t e) {
    return (f & 2) ? ei32[2 * e] : ei32[e];
}
__device__ __forceinline__ int load_col(const int* ei32, int f, size_t e) {
    return (f & 2) ? ei32[2 * ((size_t)N_EDGES + e)] : ei32[(size_t)N_EDGES + e];
}
__device__ __forceinline__ float load_w(const void* ew, int f, size_t e) {
    return (f & 1) ? __bfloat162float(((const bf16*)ew)[e]) : ((const float*)ew)[e];
}

// ---------- shared init / finalize ----------

__global__ void init_kernel(const void* __restrict__ users,
                            const void* __restrict__ items,
                            void* __restrict__ out,
                            float* __restrict__ A,
                            float* __restrict__ B,
                            float* __restrict__ ACC,
                            const int* __restrict__ flag,
                            int zeroB)
{
    int gid = blockIdx.x * blockDim.x + threadIdx.x;
    if (gid >= NODE_ELEMS) return;
    const bool isb = ((*flag) & 1);
    float v;
    if (gid < U_ELEMS) {
        if (isb) { bf16 b = ((const bf16*)users)[gid]; v = __bfloat162float(b); ((bf16*)out)[U_ELEMS + gid] = b; }
        else     { float fv = ((const float*)users)[gid]; v = fv; ((float*)out)[U_ELEMS + gid] = fv; }
    } else {
        int ii = gid - U_ELEMS;
        if (isb) { bf16 b = ((const bf16*)items)[ii]; v = __bfloat162float(b); ((bf16*)out)[2 * U_ELEMS + I_ELEMS + ii] = b; }
        else     { float fv = ((const float*)items)[ii]; v = fv; ((float*)out)[2 * U_ELEMS + I_ELEMS + ii] = fv; }
    }
    A[gid]   = v;
    if (zeroB) B[gid] = 0.0f;   // only the atomic fallback needs a zeroed target
    ACC[gid] = v;
}

__global__ void finalize_kernel(const float* __restrict__ acc,
                                void* __restrict__ out,
                                const int* __restrict__ flag)
{
    int gid = blockIdx.x * blockDim.x + threadIdx.x;
    if (gid >= NODE_ELEMS) return;
    const bool isb = ((*flag) & 1);
    float v = acc[gid] * 0.25f;
    size_t o = (gid < U_ELEMS) ? (size_t)gid : (size_t)(2 * U_ELEMS + (gid - U_ELEMS));
    if (isb) ((bf16*)out)[o]  = __float2bfloat16(v);
    else     ((float*)out)[o] = v;
}

// ---------- CSR build ----------

__global__ void zero_cnt_kernel(int* __restrict__ cnt)
{
    int gid = blockIdx.x * blockDim.x + threadIdx.x;
    if (gid < N_NODES) cnt[gid] = 0;
}

__global__ void hist_kernel(const int* __restrict__ ei32,
                            int* __restrict__ cnt,
                            const int* __restrict__ flag)
{
    int e = blockIdx.x * blockDim.x + threadIdx.x;
    if (e >= N_EDGES) return;
    atomicAdd(&cnt[load_row(ei32, *flag, e)], 1);
}

// single-block exclusive scan over N_NODES counts -> rowptr[N_NODES+1], fill_off
__global__ void scan_kernel(const int* __restrict__ cnt,
                            int* __restrict__ rowptr,
                            int* __restrict__ fill_off)
{
    __shared__ int ls[16];
    __shared__ int s_carry;
    const int t = threadIdx.x;          // 1024 threads = 16 waves
    const int lane = t & 63;
    const int wv = t >> 6;
    if (t == 0) s_carry = 0;
    __syncthreads();
    for (int base = 0; base < N_NODES; base += 1024) {
        int i = base + t;
        int x = (i < N_NODES) ? cnt[i] : 0;
        int v = x;                       // wave inclusive scan
        #pragma unroll
        for (int d = 1; d < 64; d <<= 1) {
            int y = __shfl_up(v, d, 64);
            if (lane >= d) v += y;
        }
        if (lane == 63) ls[wv] = v;
        __syncthreads();
        if (wv == 0 && lane < 16) {
            int s = ls[lane];
            #pragma unroll
            for (int d = 1; d < 16; d <<= 1) {
                int y = __shfl_up(s, d, 64);
                if (lane >= d) s += y;
            }
            ls[lane] = s;                // inclusive over wave sums
        }
        __syncthreads();
        int waveoff = (wv == 0) ? 0 : ls[wv - 1];
        int carry = s_carry;
        int excl = carry + waveoff + v - x;
        if (i < N_NODES) { rowptr[i] = excl; fill_off[i] = excl; }
        __syncthreads();                 // everyone has read s_carry
        if (t == 1023) s_carry = carry + ls[15];
        __syncthreads();
    }
    if (t == 0) rowptr[N_NODES] = s_carry;   // == N_EDGES
}

__global__ void fill_kernel(const int* __restrict__ ei32,
                            const void* __restrict__ ew,
                            int* __restrict__ fill_off,
                            int* __restrict__ csr_col,
                            float* __restrict__ csr_w,
                            const int* __restrict__ flag)
{
    int e = blockIdx.x * blockDim.x + threadIdx.x;
    if (e >= N_EDGES) return;
    const int f = *flag;
    int row = load_row(ei32, f, e);
    int pos = atomicAdd(&fill_off[row], 1);
    csr_col[pos] = load_col(ei32, f, e);
    csr_w[pos]   = load_w(ew, f, e);
}

// ---------- gather-only hop: wave per row, lane = emb dim ----------

__global__ void hop_kernel(const int* __restrict__ rowptr,
                           const int* __restrict__ csr_col,
                           const float* __restrict__ csr_w,
                           const float* __restrict__ prev,
                           float* __restrict__ next,
                           float* __restrict__ acc)
{
    int row  = blockIdx.x * (blockDim.x >> 6) + (threadIdx.x >> 6);
    int lane = threadIdx.x & 63;
    if (row >= N_NODES) return;
    int s = rowptr[row], e = rowptr[row + 1];
    float a0 = 0.0f, a1 = 0.0f;
    int k = s;
    for (; k + 1 < e; k += 2) {
        int   c0 = csr_col[k],     c1 = csr_col[k + 1];
        float w0 = csr_w[k],       w1 = csr_w[k + 1];
        a0 += w0 * prev[(size_t)c0 * EMB + lane];
        a1 += w1 * prev[(size_t)c1 * EMB + lane];
    }
    if (k < e)
        a0 += csr_w[k] * prev[(size_t)csr_col[k] * EMB + lane];
    float a = a0 + a1;
    size_t o = (size_t)row * EMB + lane;
    next[o] = a;
    acc[o] += a;
}

// ---------- R3 atomic fallback ----------

__global__ void scatter_kernel(const int* __restrict__ ei32,
                               const void* __restrict__ ew,
                               const float* __restrict__ prev,
                               float* __restrict__ next,
                               const int* __restrict__ flag)
{
    int gid = blockIdx.x * blockDim.x + threadIdx.x;
    if (gid >= N_EDGES * 16) return;
    const int f = *flag;
    int e = gid >> 4;
    int j = (gid & 15) << 2;
    int row = load_row(ei32, f, e);
    int col = load_col(ei32, f, e);
    float w = load_w(ew, f, e);
    const float4 v = *reinterpret_cast<const float4*>(prev + (size_t)col * EMB + j);
    float* dst = next + (size_t)row * EMB + j;
    unsafeAtomicAdd(dst + 0, w * v.x);
    unsafeAtomicAdd(dst + 1, w * v.y);
    unsafeAtomicAdd(dst + 2, w * v.z);
    unsafeAtomicAdd(dst + 3, w * v.w);
}

__global__ void accum_zero_kernel(float* __restrict__ acc,
                                  const float* __restrict__ next,
                                  float* __restrict__ prevz)
{
    int gid = blockIdx.x * blockDim.x + threadIdx.x;
    if (gid >= NODE_ELEMS) return;
    acc[gid] += next[gid];
    prevz[gid] = 0.0f;
}

__global__ void sentinel_kernel(unsigned int* __restrict__ out, int nwords)
{
    int gid = blockIdx.x * blockDim.x + threadIdx.x;
    if (gid < nwords) out[gid] = 0x447A447Au;
}

extern "C" void kernel_launch(void* const* d_in, const int* in_sizes, int n_in,
                              void* d_out, int out_size, void* d_ws, size_t ws_size,
                              hipStream_t stream)
{
    const void* users = d_in[0];
    const void* items = d_in[1];
    const int*  ei32  = (const int*)d_in[2];
    const void* ew    = d_in[3];

    char* wsb  = (char*)d_ws;
    int*  flag = (int*)wsb;
    float* A   = (float*)(wsb + 256);
    float* B   = A + (size_t)NODE_ELEMS;
    float* ACC = B + (size_t)NODE_ELEMS;
    char* p    = (char*)(ACC + (size_t)NODE_ELEMS);
    int*  rowptr   = (int*)p;                      p += (N_NODES + 2) * sizeof(int);
    int*  fill_off = (int*)p;                      p += N_NODES * sizeof(int);
    int*  cnt      = (int*)p;                      p += N_NODES * sizeof(int);
    int*  csr_col  = (int*)p;                      p += (size_t)N_EDGES * sizeof(int);
    float* csr_w   = (float*)p;                    p += (size_t)N_EDGES * sizeof(float);

    const size_t need_csr    = (size_t)(p - wsb);
    const size_t need_atomic = 256 + 3 * (size_t)NODE_ELEMS * sizeof(float);
    const int BLK = 256;
    const int node_blocks = (NODE_ELEMS + BLK - 1) / BLK;
    const int row_blocks  = (N_NODES + 3) / 4;              // 4 waves (rows) per block
    const int edge_blocks = (N_EDGES + BLK - 1) / BLK;

    if (ws_size >= need_csr) {
        detect_kernel<<<1, BLK, 0, stream>>>((const unsigned short*)users, ei32, flag);
        init_kernel<<<node_blocks, BLK, 0, stream>>>(users, items, d_out, A, B, ACC, flag, 0);
        zero_cnt_kernel<<<(N_NODES + BLK - 1) / BLK, BLK, 0, stream>>>(cnt);
        hist_kernel<<<edge_blocks, BLK, 0, stream>>>(ei32, cnt, flag);
        scan_kernel<<<1, 1024, 0, stream>>>(cnt, rowptr, fill_off);
        fill_kernel<<<edge_blocks, BLK, 0, stream>>>(ei32, ew, fill_off, csr_col, csr_w, flag);

        float* prev = A;
        float* nxt  = B;
        for (int h = 0; h < 3; ++h) {
            hop_kernel<<<row_blocks, BLK, 0, stream>>>(rowptr, csr_col, csr_w, prev, nxt, ACC);
            float* t = prev; prev = nxt; nxt = t;
        }
        finalize_kernel<<<node_blocks, BLK, 0, stream>>>(ACC, d_out, flag);
    } else if (ws_size >= need_atomic) {
        const int sedge_blocks = (N_EDGES * 16 + BLK - 1) / BLK;
        detect_kernel<<<1, BLK, 0, stream>>>((const unsigned short*)users, ei32, flag);
        init_kernel<<<node_blocks, BLK, 0, stream>>>(users, items, d_out, A, B, ACC, flag, 1);
        float* prev = A;
        float* nxt  = B;
        for (int h = 0; h < 3; ++h) {
            scatter_kernel<<<sedge_blocks, BLK, 0, stream>>>(ei32, ew, prev, nxt, flag);
            accum_zero_kernel<<<node_blocks, BLK, 0, stream>>>(ACC, nxt, prev);
            float* t = prev; prev = nxt; nxt = t;
        }
        finalize_kernel<<<node_blocks, BLK, 0, stream>>>(ACC, d_out, flag);
    } else {
        int nwords = out_size / 2;
        sentinel_kernel<<<(nwords + BLK - 1) / BLK, BLK, 0, stream>>>((unsigned int*)d_out, nwords);
    }
}